// Round 6
// baseline (11146.072 us; speedup 1.0000x reference)
//
#include <hip/hip_runtime.h>
#include <stdint.h>
#include <stddef.h>

// BaselinePointerNetwork: B=1024, N=128, H=128, T=256
// Pipeline: e1 (emb,Q,K,V) -> e2 (attention -> att_emb) -> e3 (A1, P) -> decode
// ws regions (64MiB each): R0 = Q -> att -> A1, R1 = K -> P, R2 = V
// RNG: JAX threefry2x32, PARTITIONABLE semantics:
//   split (foldlike): key_t = (o0,o1) of tf(key,(0,t))
//   random_bits(32):  bits  = o0 ^ o1 of tf(key_t,(hi(i),lo(i))), i = b*128+n

#define NEGV (-1e9f)

__device__ __forceinline__ uint32_t rotl32(uint32_t v, int d) { return (v << d) | (v >> (32 - d)); }

__device__ __forceinline__ void threefry2x32(uint32_t k0, uint32_t k1, uint32_t c0, uint32_t c1,
                                             uint32_t& o0, uint32_t& o1) {
  uint32_t k2 = k0 ^ k1 ^ 0x1BD11BDAu;
  uint32_t x0 = c0 + k0, x1 = c1 + k1;
  x0 += x1; x1 = rotl32(x1, 13); x1 ^= x0;
  x0 += x1; x1 = rotl32(x1, 15); x1 ^= x0;
  x0 += x1; x1 = rotl32(x1, 26); x1 ^= x0;
  x0 += x1; x1 = rotl32(x1, 6);  x1 ^= x0;
  x0 += k1; x1 += k2 + 1u;
  x0 += x1; x1 = rotl32(x1, 17); x1 ^= x0;
  x0 += x1; x1 = rotl32(x1, 29); x1 ^= x0;
  x0 += x1; x1 = rotl32(x1, 16); x1 ^= x0;
  x0 += x1; x1 = rotl32(x1, 24); x1 ^= x0;
  x0 += k2; x1 += k0 + 2u;
  x0 += x1; x1 = rotl32(x1, 13); x1 ^= x0;
  x0 += x1; x1 = rotl32(x1, 15); x1 ^= x0;
  x0 += x1; x1 = rotl32(x1, 26); x1 ^= x0;
  x0 += x1; x1 = rotl32(x1, 6);  x1 ^= x0;
  x0 += k0; x1 += k1 + 3u;
  x0 += x1; x1 = rotl32(x1, 17); x1 ^= x0;
  x0 += x1; x1 = rotl32(x1, 29); x1 ^= x0;
  x0 += x1; x1 = rotl32(x1, 16); x1 ^= x0;
  x0 += x1; x1 = rotl32(x1, 24); x1 ^= x0;
  x0 += k1; x1 += k2 + 4u;
  x0 += x1; x1 = rotl32(x1, 13); x1 ^= x0;
  x0 += x1; x1 = rotl32(x1, 15); x1 ^= x0;
  x0 += x1; x1 = rotl32(x1, 26); x1 ^= x0;
  x0 += x1; x1 = rotl32(x1, 6);  x1 ^= x0;
  x0 += k2; x1 += k0 + 5u;
  o0 = x0; o1 = x1;
}

__device__ __forceinline__ float gumbel_from(uint32_t kA, uint32_t kB, uint32_t idx) {
  uint32_t o0, o1;
  threefry2x32(kA, kB, 0u, idx, o0, o1);
  uint32_t bits = o0 ^ o1;                 // partitionable: xor of both output words
  uint32_t mb = bits >> 9;
  float u = (mb == 0u) ? 1.17549435e-38f : (float)mb * 1.1920928955078125e-07f;
  return -logf(-logf(u));
}

// out[n][h] = sum_k Alds[n][k]*W[k][h] + bias[h]; W staged in 16-row chunks with
// register prefetch of chunk ks+16 overlapping compute of chunk ks (same fmaf order).
__device__ void mm128(const float* Alds, float* wst,
                      const float* __restrict__ W, const float* __restrict__ bias,
                      float* outg, int t) {
  int wv = t >> 6, lane = t & 63;
  int j0 = lane * 2;
  float b0 = 0.f, b1 = 0.f;
  if (bias) { b0 = bias[j0]; b1 = bias[j0 + 1]; }
  int r0 = wv * 32;
  float acc0[4][8], acc1[4][8];
#pragma unroll
  for (int g = 0; g < 4; ++g)
#pragma unroll
    for (int r = 0; r < 8; ++r) { acc0[g][r] = b0; acc1[g][r] = b1; }

  // chunk 0: load -> store -> barrier (previous user of wst is past its last barrier)
  float4 pf0 = *(const float4*)&W[t * 4];
  float4 pf1 = *(const float4*)&W[1024 + t * 4];
  *(float4*)&wst[t * 4] = pf0;
  *(float4*)&wst[1024 + t * 4] = pf1;
  __syncthreads();

  for (int ks = 0; ks < 128; ks += 16) {
    if (ks < 112) {           // issue next chunk's global loads early (latency hidden)
      pf0 = *(const float4*)&W[(ks + 16) * 128 + t * 4];
      pf1 = *(const float4*)&W[(ks + 16) * 128 + 1024 + t * 4];
    }
#pragma unroll
    for (int k4 = 0; k4 < 16; k4 += 4) {
      float2 w[4];
#pragma unroll
      for (int kk = 0; kk < 4; ++kk) w[kk] = *(const float2*)&wst[(k4 + kk) * 128 + j0];
#pragma unroll
      for (int g = 0; g < 4; ++g)
#pragma unroll
        for (int r = 0; r < 8; ++r) {
          float4 a = *(const float4*)&Alds[(r0 + g * 8 + r) * 128 + ks + k4];
          acc0[g][r] = fmaf(a.x, w[0].x, acc0[g][r]); acc1[g][r] = fmaf(a.x, w[0].y, acc1[g][r]);
          acc0[g][r] = fmaf(a.y, w[1].x, acc0[g][r]); acc1[g][r] = fmaf(a.y, w[1].y, acc1[g][r]);
          acc0[g][r] = fmaf(a.z, w[2].x, acc0[g][r]); acc1[g][r] = fmaf(a.z, w[2].y, acc1[g][r]);
          acc0[g][r] = fmaf(a.w, w[3].x, acc0[g][r]); acc1[g][r] = fmaf(a.w, w[3].y, acc1[g][r]);
        }
    }
    __syncthreads();          // everyone done reading wst chunk ks
    if (ks < 112) {
      *(float4*)&wst[t * 4] = pf0;
      *(float4*)&wst[1024 + t * 4] = pf1;
      __syncthreads();        // wst chunk ks+16 ready
    }
  }
#pragma unroll
  for (int g = 0; g < 4; ++g)
#pragma unroll
    for (int r = 0; r < 8; ++r) {
      int n = r0 + g * 8 + r;
      float2 o; o.x = acc0[g][r]; o.y = acc1[g][r];
      *(float2*)&outg[n * 128 + j0] = o;
    }
}

// ---- E1: emb -> Q, K, V ----
__global__ __launch_bounds__(256, 2) void pn_e1(
    const float* __restrict__ coords, const float* __restrict__ demands,
    const float* __restrict__ W_emb, const float* __restrict__ b_emb,
    const float* __restrict__ Wq, const float* __restrict__ bq,
    const float* __restrict__ Wk, const float* __restrict__ bk,
    const float* __restrict__ Wv, const float* __restrict__ bv,
    float* Qo, float* Ko, float* Vo) {
  __shared__ float emb[128 * 128];
  __shared__ float wst[16 * 128];
  __shared__ float nfx[128], nfy[128], nfd[128];
  int b = blockIdx.x, t = threadIdx.x;
  if (t < 128) {
    float2 c = ((const float2*)coords)[b * 128 + t];
    nfx[t] = c.x; nfy[t] = c.y; nfd[t] = demands[b * 128 + t];
  }
  __syncthreads();
  {
    int h = t >> 1, n0 = (t & 1) * 64;
    float w0 = W_emb[h], w1 = W_emb[128 + h], w2 = W_emb[256 + h], be = b_emb[h];
    for (int n = n0; n < n0 + 64; ++n) {
      float e = nfx[n] * w0;
      e = fmaf(nfy[n], w1, e);
      e = fmaf(nfd[n], w2, e);
      e = e + be;
      emb[n * 128 + h] = e;
    }
  }
  __syncthreads();
  mm128(emb, wst, Wq, bq, Qo + (size_t)b * 16384, t);
  mm128(emb, wst, Wk, bk, Ko + (size_t)b * 16384, t);
  mm128(emb, wst, Wv, bv, Vo + (size_t)b * 16384, t);
}

// ---- E2: att_emb = softmax(Q K^T / sqrt(H)) @ V ----
__global__ __launch_bounds__(256, 2) void pn_e2(
    const float* Qg, const float* __restrict__ Kg, const float* __restrict__ Vg, float* atto) {
  __shared__ float Ks[128 * 132];
  __shared__ float qb[4 * 512];
  int b = blockIdx.x, t = threadIdx.x;
  int wv = t >> 6, lane = t & 63;
  const float sden = sqrtf(128.0f);
  for (int i = t; i < 16384; i += 256) {
    int m = i >> 7, k = i & 127;
    Ks[m * 132 + k] = Kg[(size_t)b * 16384 + i];
  }
  __syncthreads();
  const float* Vb = Vg + (size_t)b * 16384;
  for (int pass = 0; pass < 8; ++pass) {
    int nb = pass * 16 + wv * 4;
    for (int i = lane; i < 512; i += 64) qb[wv * 512 + i] = Qg[(size_t)b * 16384 + nb * 128 + i];
    __syncthreads();
    float s0[4] = {0.f, 0.f, 0.f, 0.f}, s1[4] = {0.f, 0.f, 0.f, 0.f};
    for (int k = 0; k < 128; k += 4) {
      float4 ka = *(const float4*)&Ks[lane * 132 + k];
      float4 kb = *(const float4*)&Ks[(lane + 64) * 132 + k];
#pragma unroll
      for (int r = 0; r < 4; ++r) {
        float4 q = *(const float4*)&qb[wv * 512 + r * 128 + k];
        s0[r] = fmaf(q.x, ka.x, s0[r]); s0[r] = fmaf(q.y, ka.y, s0[r]);
        s0[r] = fmaf(q.z, ka.z, s0[r]); s0[r] = fmaf(q.w, ka.w, s0[r]);
        s1[r] = fmaf(q.x, kb.x, s1[r]); s1[r] = fmaf(q.y, kb.y, s1[r]);
        s1[r] = fmaf(q.z, kb.z, s1[r]); s1[r] = fmaf(q.w, kb.w, s1[r]);
      }
    }
    float p0[4], p1[4];
#pragma unroll
    for (int r = 0; r < 4; ++r) {
      float a0 = s0[r] / sden, a1 = s1[r] / sden;
      float mx = fmaxf(a0, a1);
#pragma unroll
      for (int off = 1; off < 64; off <<= 1) mx = fmaxf(mx, __shfl_xor(mx, off));
      float e0 = expf(a0 - mx), e1 = expf(a1 - mx);
      float sm = e0 + e1;
#pragma unroll
      for (int off = 1; off < 64; off <<= 1) sm += __shfl_xor(sm, off);
      p0[r] = e0 / sm; p1[r] = e1 / sm;
    }
#pragma unroll
    for (int r = 0; r < 4; ++r) {
      qb[wv * 512 + r * 128 + lane] = p0[r];
      qb[wv * 512 + r * 128 + lane + 64] = p1[r];
    }
    __syncthreads();
    float o0[4] = {0.f, 0.f, 0.f, 0.f}, o1[4] = {0.f, 0.f, 0.f, 0.f};
    for (int m4 = 0; m4 < 128; m4 += 4) {
      float4 p[4];
#pragma unroll
      for (int r = 0; r < 4; ++r) p[r] = *(const float4*)&qb[wv * 512 + r * 128 + m4];
#pragma unroll
      for (int mm = 0; mm < 4; ++mm) {
        float v0 = Vb[(m4 + mm) * 128 + lane];
        float v1 = Vb[(m4 + mm) * 128 + lane + 64];
#pragma unroll
        for (int r = 0; r < 4; ++r) {
          float pv = (mm == 0) ? p[r].x : (mm == 1) ? p[r].y : (mm == 2) ? p[r].z : p[r].w;
          o0[r] = fmaf(pv, v0, o0[r]);
          o1[r] = fmaf(pv, v1, o1[r]);
        }
      }
    }
#pragma unroll
    for (int r = 0; r < 4; ++r) {
      atto[(size_t)b * 16384 + (nb + r) * 128 + lane] = o0[r];
      atto[(size_t)b * 16384 + (nb + r) * 128 + lane + 64] = o1[r];
    }
    __syncthreads();
  }
}

// ---- E3: A1 = att@Wp1[:128] + bp1 ; P = att@Wp1[128:] ----
__global__ __launch_bounds__(256, 2) void pn_e3(
    const float* attg, const float* __restrict__ Wp1,
    const float* __restrict__ bp1, float* A1o, float* Po) {
  __shared__ float att[128 * 128];
  __shared__ float wst[16 * 128];
  int b = blockIdx.x, t = threadIdx.x;
  for (int i = t; i < 16384; i += 256) att[i] = attg[(size_t)b * 16384 + i];
  __syncthreads();
  mm128(att, wst, Wp1, bp1, A1o + (size_t)b * 16384, t);
  mm128(att, wst, Wp1 + 16384, (const float*)0, Po + (size_t)b * 16384, t);
}

// ---- decode v6 ----
// P natural [n][h]: phase-A column reads are conflict-free (consecutive lanes ->
// consecutive addresses); visited mask applied from wave-uniform SGPRs
// (readfirstlane + select 0/1 -> v_fmac with SGPR operand) -> no mask LDS traffic.
// Waves 0-1: state (replicated) + A + C. Waves 2-3: stateless (gumbel prefetch + B).
// 2 barriers/step; done propagated via LDS flag read after bar1 (uniform break).
// Hazards: c1 A(w01,pre-bar1)->B(all); B reads vs A(s+1): A(s+1) by w01 after C(s)
//   which is post-bar2(s), and w23 finished B(s) reads pre-bar2(s).  scv B(pre-bar2)
//   ->C; C reads vs B(s+1) ordered by bar1(s+1).  gv slots distinct mod 3 for all
//   concurrent read/write pairs.  doneFlag C(s)->bar1(s+1)->read.
__global__ __launch_bounds__(256, 2) void pn_decode(
    const float* __restrict__ A1g, const float* __restrict__ Pg,
    const float* __restrict__ demands, const float* __restrict__ caps,
    const float* __restrict__ Wp2, const float* __restrict__ bp2, float* out) {
  __shared__ __align__(16) float P[128 * 128];   // natural [n][h]
  __shared__ __align__(16) float c1[128];
  __shared__ float scv[128];
  __shared__ float dem[128];
  __shared__ float gv[3][128];                   // triple-buffered gumbels
  __shared__ int acts[256];
  __shared__ uint32_t keyA[256], keyB[256];
  __shared__ int doneFlag;

  int b = blockIdx.x, t = threadIdx.x;
  int wave = t >> 6, lane = t & 63;
  // step keys: foldlike split -> key_t = (o0,o1) of tf((0,42),(0,t))
  { uint32_t o0, o1; threefry2x32(0u, 42u, 0u, (uint32_t)t, o0, o1); keyA[t] = o0; keyB[t] = o1; }
  for (int i = t; i < 16384; i += 256) P[i] = Pg[(size_t)b * 16384 + i];
  // A1 fragment + Wp2 fragment in registers: thread t owns node nrow=t>>1, half=t&1
  int nrow = t >> 1, half = t & 1;
  float a1r[64], w2r[64];
  {
    const float4* asrc = (const float4*)(A1g + (size_t)b * 16384 + nrow * 128 + half * 64);
    const float4* wsrc = (const float4*)(Wp2 + half * 64);
#pragma unroll
    for (int j = 0; j < 16; ++j) {
      float4 v = asrc[j];
      a1r[4 * j] = v.x; a1r[4 * j + 1] = v.y; a1r[4 * j + 2] = v.z; a1r[4 * j + 3] = v.w;
      float4 w = wsrc[j];
      w2r[4 * j] = w.x; w2r[4 * j + 1] = w.y; w2r[4 * j + 2] = w.z; w2r[4 * j + 3] = w.w;
    }
  }
  if (t < 128) dem[t] = demands[b * 128 + t];
  acts[t] = 0;
  if (t == 0) doneFlag = 0;
  float capv = caps[b];
  float bp2v = bp2[0];
  float dem0 = 0.f, dem1 = 0.f;
  if (wave < 2) {
    dem0 = demands[b * 128 + lane];        // n0 = lane
    dem1 = demands[b * 128 + lane + 64];   // n1 = lane + 64
  }
  // replicated state on waves 0-1 only (uniform within each wave)
  unsigned long long vism0 = 0ull, vism1 = 0ull;
  float rc = capv, lps = 0.f;
  int at = 1, done = 0, vc = 0;
  __syncthreads();
  // gumbels for step 0 -> slot 0
  if (t >= 128) gv[0][t - 128] = gumbel_from(keyA[0], keyB[0], (uint32_t)(b * 128 + (t - 128)));

  int rslot = 0;
  for (int step = 0; step < 256; ++step) {
    int wslot = rslot + 1; if (wslot == 3) wslot = 0;
    // A: waves 0-1: c1[h] = masked ascending-n sum of P[:,h] / cnt  (SGPR mask, fmaf 0/1)
    //    waves 2-3: prefetch next step's gumbels
    if (t < 128) {
      uint32_t m0 = __builtin_amdgcn_readfirstlane((uint32_t)(vism0 & 0xffffffffull));
      uint32_t m1 = __builtin_amdgcn_readfirstlane((uint32_t)(vism0 >> 32));
      uint32_t m2 = __builtin_amdgcn_readfirstlane((uint32_t)(vism1 & 0xffffffffull));
      uint32_t m3 = __builtin_amdgcn_readfirstlane((uint32_t)(vism1 >> 32));
      float cnt = fmaxf((float)(128 - vc), 1.f);
      const float* pc = &P[t];
      float acc = 0.f;
#pragma unroll
      for (int n = 0; n < 128; n += 2) {
        float pa = pc[n * 128];
        float pb = pc[(n + 1) * 128];
        uint32_t wa = (n < 32) ? m0 : (n < 64) ? m1 : (n < 96) ? m2 : m3;
        uint32_t wb = ((n + 1) < 32) ? m0 : ((n + 1) < 64) ? m1 : ((n + 1) < 96) ? m2 : m3;
        float sa = ((wa >> (n & 31)) & 1u) ? 0.f : 1.f;
        float sb = ((wb >> ((n + 1) & 31)) & 1u) ? 0.f : 1.f;
        acc = fmaf(pa, sa, acc);
        acc = fmaf(pb, sb, acc);
      }
      c1[t] = acc / cnt;
    } else if (step < 255) {
      int n = t - 128;
      gv[wslot][n] = gumbel_from(keyA[step + 1], keyB[step + 1], (uint32_t)(b * 128 + n));
    }
    __syncthreads();  // bar1
    if (doneFlag) break;                          // uniform across block

    // B: sc[n] = relu(A1[n]+c1).Wp2 + bp2  (all waves, 2 threads per node)
    {
      const float* crow = &c1[half * 64];
      float acc = 0.f;
#pragma unroll
      for (int q = 0; q < 16; ++q) {
        float4 c4 = *(const float4*)&crow[q * 4];
        float x;
        x = a1r[4 * q] + c4.x;     x = fmaxf(x, 0.f); acc = fmaf(x, w2r[4 * q], acc);
        x = a1r[4 * q + 1] + c4.y; x = fmaxf(x, 0.f); acc = fmaf(x, w2r[4 * q + 1], acc);
        x = a1r[4 * q + 2] + c4.z; x = fmaxf(x, 0.f); acc = fmaf(x, w2r[4 * q + 2], acc);
        x = a1r[4 * q + 3] + c4.w; x = fmaxf(x, 0.f); acc = fmaf(x, w2r[4 * q + 3], acc);
      }
      float other = __shfl_xor(acc, 1);
      if (half == 0) scv[nrow] = (acc + other) + bp2v;
    }
    __syncthreads();  // bar2

    // C: waves 0-1 (replicated): masks + argmax + state; wave 0 also lps/acts/doneFlag
    if (t < 128) {
      float g0 = gv[rslot][lane], g1 = gv[rslot][lane + 64];
      bool mk0 = (lane == 0) ? (at != 0)
                             : ((((vism0 >> lane) & 1ull) != 0ull) || (dem0 > rc));
      bool mk1 = (((vism1 >> lane) & 1ull) != 0ull) || (dem1 > rc);
      unsigned long long bl0 = __ballot(mk0 ? 1 : 0);
      unsigned long long bl1 = __ballot(mk1 ? 1 : 0);
      int d = done;
      if (vc == 127 && at) d = 1;
      if ((bl0 == ~0ull) && (bl1 == ~0ull) && at) d = 1;
      if (lane == 0) mk0 = (at && !d);           // final depot mask
      float sc0 = scv[lane], sc1 = scv[lane + 64];
      float lg0 = mk0 ? NEGV : sc0;
      float lg1 = mk1 ? NEGV : sc1;
      float v0g = g0 + lg0, v1g = g1 + lg1;
      float v; int idx;
      if (v1g > v0g) { v = v1g; idx = lane + 64; } else { v = v0g; idx = lane; }
      float mx = fmaxf(lg0, lg1);
#pragma unroll
      for (int off = 1; off < 64; off <<= 1) {
        float ov = __shfl_xor(v, off);
        int oi = __shfl_xor(idx, off);
        if (ov > v || (ov == v && oi < idx)) { v = ov; idx = oi; }
        mx = fmaxf(mx, __shfl_xor(mx, off));
      }
      int a = d ? 0 : idx;
      if (wave == 0) {
        float e = expf(lg0 - mx) + expf(lg1 - mx);
#pragma unroll
        for (int off = 1; off < 64; off <<= 1) e += __shfl_xor(e, off);
        if (lane == 0) {
          float sel = d ? 0.f : ((scv[idx] - mx) - logf(e));
          lps += sel;
          acts[step] = a;
          doneFlag = d;
        }
      }
      if (!d) {
        if (a == 0) { rc = capv; at = 1; }
        else {
          rc = rc - dem[a];
          at = 0; vc = vc + 1;
          if (a < 64) vism0 |= (1ull << a); else vism1 |= (1ull << (a - 64));
        }
      }
      done = d;
    }
    rslot = wslot;
  }

  __syncthreads();
  out[(size_t)b * 256 + t] = (float)acts[t];
  if (t == 0) out[(size_t)1024 * 256 + b] = lps;
}

extern "C" void kernel_launch(void* const* d_in, const int* in_sizes, int n_in,
                              void* d_out, int out_size, void* d_ws, size_t ws_size,
                              hipStream_t stream) {
  (void)in_sizes; (void)n_in; (void)out_size; (void)ws_size;
  const float* coords  = (const float*)d_in[0];
  const float* demands = (const float*)d_in[1];
  const float* caps    = (const float*)d_in[2];
  const float* W_emb   = (const float*)d_in[3];
  const float* b_emb   = (const float*)d_in[4];
  const float* Wq      = (const float*)d_in[5];
  const float* bq      = (const float*)d_in[6];
  const float* Wk      = (const float*)d_in[7];
  const float* bk      = (const float*)d_in[8];
  const float* Wv      = (const float*)d_in[9];
  const float* bv      = (const float*)d_in[10];
  const float* Wp1     = (const float*)d_in[11];
  const float* bp1     = (const float*)d_in[12];
  const float* Wp2     = (const float*)d_in[13];
  const float* bp2     = (const float*)d_in[14];

  float* ws = (float*)d_ws;
  const size_t R = (size_t)1024 * 128 * 128;  // 64 MiB per region
  float* R0 = ws;           // Q -> att_emb -> A1
  float* R1 = ws + R;       // K -> P
  float* R2 = ws + 2 * R;   // V

  pn_e1<<<1024, 256, 0, stream>>>(coords, demands, W_emb, b_emb, Wq, bq, Wk, bk, Wv, bv, R0, R1, R2);
  pn_e2<<<1024, 256, 0, stream>>>(R0, R1, R2, R0);
  pn_e3<<<1024, 256, 0, stream>>>(R0, Wp1, bp1, R0, R1);
  pn_decode<<<1024, 256, 0, stream>>>(R0, R1, demands, caps, Wp2, bp2, (float*)d_out);
}

// Round 7
// 2300.530 us; speedup vs baseline: 4.8450x; 4.8450x over previous
//
#include <hip/hip_runtime.h>
#include <stdint.h>
#include <stddef.h>

// BaselinePointerNetwork: B=1024, N=128, H=128, T=256
// Pipeline: e1 (emb,Q,K,V) -> e2 (attention -> att_emb) -> e3 (A1, P) -> decode
// ws regions (64MiB each): R0 = Q -> att -> A1, R1 = K -> P, R2 = V
// RNG: JAX threefry2x32, PARTITIONABLE semantics:
//   split (foldlike): key_t = (o0,o1) of tf(key,(0,t))
//   random_bits(32):  bits  = o0 ^ o1 of tf(key_t,(hi(i),lo(i))), i = b*128+n

#define NEGV (-1e9f)

__device__ __forceinline__ uint32_t rotl32(uint32_t v, int d) { return (v << d) | (v >> (32 - d)); }

__device__ __forceinline__ void threefry2x32(uint32_t k0, uint32_t k1, uint32_t c0, uint32_t c1,
                                             uint32_t& o0, uint32_t& o1) {
  uint32_t k2 = k0 ^ k1 ^ 0x1BD11BDAu;
  uint32_t x0 = c0 + k0, x1 = c1 + k1;
  x0 += x1; x1 = rotl32(x1, 13); x1 ^= x0;
  x0 += x1; x1 = rotl32(x1, 15); x1 ^= x0;
  x0 += x1; x1 = rotl32(x1, 26); x1 ^= x0;
  x0 += x1; x1 = rotl32(x1, 6);  x1 ^= x0;
  x0 += k1; x1 += k2 + 1u;
  x0 += x1; x1 = rotl32(x1, 17); x1 ^= x0;
  x0 += x1; x1 = rotl32(x1, 29); x1 ^= x0;
  x0 += x1; x1 = rotl32(x1, 16); x1 ^= x0;
  x0 += x1; x1 = rotl32(x1, 24); x1 ^= x0;
  x0 += k2; x1 += k0 + 2u;
  x0 += x1; x1 = rotl32(x1, 13); x1 ^= x0;
  x0 += x1; x1 = rotl32(x1, 15); x1 ^= x0;
  x0 += x1; x1 = rotl32(x1, 26); x1 ^= x0;
  x0 += x1; x1 = rotl32(x1, 6);  x1 ^= x0;
  x0 += k0; x1 += k1 + 3u;
  x0 += x1; x1 = rotl32(x1, 17); x1 ^= x0;
  x0 += x1; x1 = rotl32(x1, 29); x1 ^= x0;
  x0 += x1; x1 = rotl32(x1, 16); x1 ^= x0;
  x0 += x1; x1 = rotl32(x1, 24); x1 ^= x0;
  x0 += k1; x1 += k2 + 4u;
  x0 += x1; x1 = rotl32(x1, 13); x1 ^= x0;
  x0 += x1; x1 = rotl32(x1, 15); x1 ^= x0;
  x0 += x1; x1 = rotl32(x1, 26); x1 ^= x0;
  x0 += x1; x1 = rotl32(x1, 6);  x1 ^= x0;
  x0 += k2; x1 += k0 + 5u;
  o0 = x0; o1 = x1;
}

__device__ __forceinline__ float gumbel_from(uint32_t kA, uint32_t kB, uint32_t idx) {
  uint32_t o0, o1;
  threefry2x32(kA, kB, 0u, idx, o0, o1);
  uint32_t bits = o0 ^ o1;                 // partitionable: xor of both output words
  uint32_t mb = bits >> 9;
  float u = (mb == 0u) ? 1.17549435e-38f : (float)mb * 1.1920928955078125e-07f;
  return -logf(-logf(u));
}

// out[n][h] = sum_k Alds[n][k]*W[k][h] + bias[h]  (round-5 version; NO register
// prefetch — r6's pf0/pf1 spilled the 64-accumulator file to scratch: 17 GB HBM)
__device__ void mm128(const float* Alds, float* wst,
                      const float* __restrict__ W, const float* __restrict__ bias,
                      float* outg, int t) {
  int wv = t >> 6, lane = t & 63;
  int j0 = lane * 2;
  float b0 = 0.f, b1 = 0.f;
  if (bias) { b0 = bias[j0]; b1 = bias[j0 + 1]; }
  int r0 = wv * 32;
  float acc0[4][8], acc1[4][8];
#pragma unroll
  for (int g = 0; g < 4; ++g)
#pragma unroll
    for (int r = 0; r < 8; ++r) { acc0[g][r] = b0; acc1[g][r] = b1; }
  for (int ks = 0; ks < 128; ks += 16) {
    __syncthreads();
    for (int i = t; i < 2048; i += 256) wst[i] = W[ks * 128 + i];
    __syncthreads();
#pragma unroll
    for (int k4 = 0; k4 < 16; k4 += 4) {
      float2 w[4];
#pragma unroll
      for (int kk = 0; kk < 4; ++kk) w[kk] = *(const float2*)&wst[(k4 + kk) * 128 + j0];
#pragma unroll
      for (int g = 0; g < 4; ++g)
#pragma unroll
        for (int r = 0; r < 8; ++r) {
          float4 a = *(const float4*)&Alds[(r0 + g * 8 + r) * 128 + ks + k4];
          acc0[g][r] = fmaf(a.x, w[0].x, acc0[g][r]); acc1[g][r] = fmaf(a.x, w[0].y, acc1[g][r]);
          acc0[g][r] = fmaf(a.y, w[1].x, acc0[g][r]); acc1[g][r] = fmaf(a.y, w[1].y, acc1[g][r]);
          acc0[g][r] = fmaf(a.z, w[2].x, acc0[g][r]); acc1[g][r] = fmaf(a.z, w[2].y, acc1[g][r]);
          acc0[g][r] = fmaf(a.w, w[3].x, acc0[g][r]); acc1[g][r] = fmaf(a.w, w[3].y, acc1[g][r]);
        }
    }
  }
#pragma unroll
  for (int g = 0; g < 4; ++g)
#pragma unroll
    for (int r = 0; r < 8; ++r) {
      int n = r0 + g * 8 + r;
      float2 o; o.x = acc0[g][r]; o.y = acc1[g][r];
      *(float2*)&outg[n * 128 + j0] = o;
    }
}

// ---- E1: emb -> Q, K, V ----
__global__ __launch_bounds__(256, 2) void pn_e1(
    const float* __restrict__ coords, const float* __restrict__ demands,
    const float* __restrict__ W_emb, const float* __restrict__ b_emb,
    const float* __restrict__ Wq, const float* __restrict__ bq,
    const float* __restrict__ Wk, const float* __restrict__ bk,
    const float* __restrict__ Wv, const float* __restrict__ bv,
    float* Qo, float* Ko, float* Vo) {
  __shared__ float emb[128 * 128];
  __shared__ float wst[16 * 128];
  __shared__ float nfx[128], nfy[128], nfd[128];
  int b = blockIdx.x, t = threadIdx.x;
  if (t < 128) {
    float2 c = ((const float2*)coords)[b * 128 + t];
    nfx[t] = c.x; nfy[t] = c.y; nfd[t] = demands[b * 128 + t];
  }
  __syncthreads();
  {
    int h = t >> 1, n0 = (t & 1) * 64;
    float w0 = W_emb[h], w1 = W_emb[128 + h], w2 = W_emb[256 + h], be = b_emb[h];
    for (int n = n0; n < n0 + 64; ++n) {
      float e = nfx[n] * w0;
      e = fmaf(nfy[n], w1, e);
      e = fmaf(nfd[n], w2, e);
      e = e + be;
      emb[n * 128 + h] = e;
    }
  }
  __syncthreads();
  mm128(emb, wst, Wq, bq, Qo + (size_t)b * 16384, t);
  mm128(emb, wst, Wk, bk, Ko + (size_t)b * 16384, t);
  mm128(emb, wst, Wv, bv, Vo + (size_t)b * 16384, t);
}

// ---- E2: att_emb = softmax(Q K^T / sqrt(H)) @ V ----
__global__ __launch_bounds__(256, 2) void pn_e2(
    const float* Qg, const float* __restrict__ Kg, const float* __restrict__ Vg, float* atto) {
  __shared__ float Ks[128 * 132];
  __shared__ float qb[4 * 512];
  int b = blockIdx.x, t = threadIdx.x;
  int wv = t >> 6, lane = t & 63;
  const float sden = sqrtf(128.0f);
  for (int i = t; i < 16384; i += 256) {
    int m = i >> 7, k = i & 127;
    Ks[m * 132 + k] = Kg[(size_t)b * 16384 + i];
  }
  __syncthreads();
  const float* Vb = Vg + (size_t)b * 16384;
  for (int pass = 0; pass < 8; ++pass) {
    int nb = pass * 16 + wv * 4;
    for (int i = lane; i < 512; i += 64) qb[wv * 512 + i] = Qg[(size_t)b * 16384 + nb * 128 + i];
    __syncthreads();
    float s0[4] = {0.f, 0.f, 0.f, 0.f}, s1[4] = {0.f, 0.f, 0.f, 0.f};
    for (int k = 0; k < 128; k += 4) {
      float4 ka = *(const float4*)&Ks[lane * 132 + k];
      float4 kb = *(const float4*)&Ks[(lane + 64) * 132 + k];
#pragma unroll
      for (int r = 0; r < 4; ++r) {
        float4 q = *(const float4*)&qb[wv * 512 + r * 128 + k];
        s0[r] = fmaf(q.x, ka.x, s0[r]); s0[r] = fmaf(q.y, ka.y, s0[r]);
        s0[r] = fmaf(q.z, ka.z, s0[r]); s0[r] = fmaf(q.w, ka.w, s0[r]);
        s1[r] = fmaf(q.x, kb.x, s1[r]); s1[r] = fmaf(q.y, kb.y, s1[r]);
        s1[r] = fmaf(q.z, kb.z, s1[r]); s1[r] = fmaf(q.w, kb.w, s1[r]);
      }
    }
    float p0[4], p1[4];
#pragma unroll
    for (int r = 0; r < 4; ++r) {
      float a0 = s0[r] / sden, a1 = s1[r] / sden;
      float mx = fmaxf(a0, a1);
#pragma unroll
      for (int off = 1; off < 64; off <<= 1) mx = fmaxf(mx, __shfl_xor(mx, off));
      float e0 = expf(a0 - mx), e1 = expf(a1 - mx);
      float sm = e0 + e1;
#pragma unroll
      for (int off = 1; off < 64; off <<= 1) sm += __shfl_xor(sm, off);
      p0[r] = e0 / sm; p1[r] = e1 / sm;
    }
#pragma unroll
    for (int r = 0; r < 4; ++r) {
      qb[wv * 512 + r * 128 + lane] = p0[r];
      qb[wv * 512 + r * 128 + lane + 64] = p1[r];
    }
    __syncthreads();
    float o0[4] = {0.f, 0.f, 0.f, 0.f}, o1[4] = {0.f, 0.f, 0.f, 0.f};
    for (int m4 = 0; m4 < 128; m4 += 4) {
      float4 p[4];
#pragma unroll
      for (int r = 0; r < 4; ++r) p[r] = *(const float4*)&qb[wv * 512 + r * 128 + m4];
#pragma unroll
      for (int mm = 0; mm < 4; ++mm) {
        float v0 = Vb[(m4 + mm) * 128 + lane];
        float v1 = Vb[(m4 + mm) * 128 + lane + 64];
#pragma unroll
        for (int r = 0; r < 4; ++r) {
          float pv = (mm == 0) ? p[r].x : (mm == 1) ? p[r].y : (mm == 2) ? p[r].z : p[r].w;
          o0[r] = fmaf(pv, v0, o0[r]);
          o1[r] = fmaf(pv, v1, o1[r]);
        }
      }
    }
#pragma unroll
    for (int r = 0; r < 4; ++r) {
      atto[(size_t)b * 16384 + (nb + r) * 128 + lane] = o0[r];
      atto[(size_t)b * 16384 + (nb + r) * 128 + lane + 64] = o1[r];
    }
    __syncthreads();
  }
}

// ---- E3: A1 = att@Wp1[:128] + bp1 ; P = att@Wp1[128:] ----
__global__ __launch_bounds__(256, 2) void pn_e3(
    const float* attg, const float* __restrict__ Wp1,
    const float* __restrict__ bp1, float* A1o, float* Po) {
  __shared__ float att[128 * 128];
  __shared__ float wst[16 * 128];
  int b = blockIdx.x, t = threadIdx.x;
  for (int i = t; i < 16384; i += 256) att[i] = attg[(size_t)b * 16384 + i];
  __syncthreads();
  mm128(att, wst, Wp1, bp1, A1o + (size_t)b * 16384, t);
  mm128(att, wst, Wp1 + 16384, (const float*)0, Po + (size_t)b * 16384, t);
}

// ---- decode v6 (unchanged from r6; measured in isolation this round) ----
// P natural [n][h]: phase-A column reads are conflict-free; visited mask applied
// from wave-uniform SGPRs. Waves 0-1: state + A + C. Waves 2-3: gumbel prefetch + B.
// 2 barriers/step; done via LDS flag read after bar1.
__global__ __launch_bounds__(256, 2) void pn_decode(
    const float* __restrict__ A1g, const float* __restrict__ Pg,
    const float* __restrict__ demands, const float* __restrict__ caps,
    const float* __restrict__ Wp2, const float* __restrict__ bp2, float* out) {
  __shared__ __align__(16) float P[128 * 128];   // natural [n][h]
  __shared__ __align__(16) float c1[128];
  __shared__ float scv[128];
  __shared__ float dem[128];
  __shared__ float gv[3][128];                   // triple-buffered gumbels
  __shared__ int acts[256];
  __shared__ uint32_t keyA[256], keyB[256];
  __shared__ int doneFlag;

  int b = blockIdx.x, t = threadIdx.x;
  int wave = t >> 6, lane = t & 63;
  { uint32_t o0, o1; threefry2x32(0u, 42u, 0u, (uint32_t)t, o0, o1); keyA[t] = o0; keyB[t] = o1; }
  for (int i = t; i < 16384; i += 256) P[i] = Pg[(size_t)b * 16384 + i];
  int nrow = t >> 1, half = t & 1;
  float a1r[64], w2r[64];
  {
    const float4* asrc = (const float4*)(A1g + (size_t)b * 16384 + nrow * 128 + half * 64);
    const float4* wsrc = (const float4*)(Wp2 + half * 64);
#pragma unroll
    for (int j = 0; j < 16; ++j) {
      float4 v = asrc[j];
      a1r[4 * j] = v.x; a1r[4 * j + 1] = v.y; a1r[4 * j + 2] = v.z; a1r[4 * j + 3] = v.w;
      float4 w = wsrc[j];
      w2r[4 * j] = w.x; w2r[4 * j + 1] = w.y; w2r[4 * j + 2] = w.z; w2r[4 * j + 3] = w.w;
    }
  }
  if (t < 128) dem[t] = demands[b * 128 + t];
  acts[t] = 0;
  if (t == 0) doneFlag = 0;
  float capv = caps[b];
  float bp2v = bp2[0];
  float dem0 = 0.f, dem1 = 0.f;
  if (wave < 2) {
    dem0 = demands[b * 128 + lane];
    dem1 = demands[b * 128 + lane + 64];
  }
  unsigned long long vism0 = 0ull, vism1 = 0ull;
  float rc = capv, lps = 0.f;
  int at = 1, done = 0, vc = 0;
  __syncthreads();
  if (t >= 128) gv[0][t - 128] = gumbel_from(keyA[0], keyB[0], (uint32_t)(b * 128 + (t - 128)));

  int rslot = 0;
  for (int step = 0; step < 256; ++step) {
    int wslot = rslot + 1; if (wslot == 3) wslot = 0;
    if (t < 128) {
      uint32_t m0 = __builtin_amdgcn_readfirstlane((uint32_t)(vism0 & 0xffffffffull));
      uint32_t m1 = __builtin_amdgcn_readfirstlane((uint32_t)(vism0 >> 32));
      uint32_t m2 = __builtin_amdgcn_readfirstlane((uint32_t)(vism1 & 0xffffffffull));
      uint32_t m3 = __builtin_amdgcn_readfirstlane((uint32_t)(vism1 >> 32));
      float cnt = fmaxf((float)(128 - vc), 1.f);
      const float* pc = &P[t];
      float acc = 0.f;
#pragma unroll
      for (int n = 0; n < 128; n += 2) {
        float pa = pc[n * 128];
        float pb = pc[(n + 1) * 128];
        uint32_t wa = (n < 32) ? m0 : (n < 64) ? m1 : (n < 96) ? m2 : m3;
        uint32_t wb = ((n + 1) < 32) ? m0 : ((n + 1) < 64) ? m1 : ((n + 1) < 96) ? m2 : m3;
        float sa = ((wa >> (n & 31)) & 1u) ? 0.f : 1.f;
        float sb = ((wb >> ((n + 1) & 31)) & 1u) ? 0.f : 1.f;
        acc = fmaf(pa, sa, acc);
        acc = fmaf(pb, sb, acc);
      }
      c1[t] = acc / cnt;
    } else if (step < 255) {
      int n = t - 128;
      gv[wslot][n] = gumbel_from(keyA[step + 1], keyB[step + 1], (uint32_t)(b * 128 + n));
    }
    __syncthreads();  // bar1
    if (doneFlag) break;

    {
      const float* crow = &c1[half * 64];
      float acc = 0.f;
#pragma unroll
      for (int q = 0; q < 16; ++q) {
        float4 c4 = *(const float4*)&crow[q * 4];
        float x;
        x = a1r[4 * q] + c4.x;     x = fmaxf(x, 0.f); acc = fmaf(x, w2r[4 * q], acc);
        x = a1r[4 * q + 1] + c4.y; x = fmaxf(x, 0.f); acc = fmaf(x, w2r[4 * q + 1], acc);
        x = a1r[4 * q + 2] + c4.z; x = fmaxf(x, 0.f); acc = fmaf(x, w2r[4 * q + 2], acc);
        x = a1r[4 * q + 3] + c4.w; x = fmaxf(x, 0.f); acc = fmaf(x, w2r[4 * q + 3], acc);
      }
      float other = __shfl_xor(acc, 1);
      if (half == 0) scv[nrow] = (acc + other) + bp2v;
    }
    __syncthreads();  // bar2

    if (t < 128) {
      float g0 = gv[rslot][lane], g1 = gv[rslot][lane + 64];
      bool mk0 = (lane == 0) ? (at != 0)
                             : ((((vism0 >> lane) & 1ull) != 0ull) || (dem0 > rc));
      bool mk1 = (((vism1 >> lane) & 1ull) != 0ull) || (dem1 > rc);
      unsigned long long bl0 = __ballot(mk0 ? 1 : 0);
      unsigned long long bl1 = __ballot(mk1 ? 1 : 0);
      int d = done;
      if (vc == 127 && at) d = 1;
      if ((bl0 == ~0ull) && (bl1 == ~0ull) && at) d = 1;
      if (lane == 0) mk0 = (at && !d);
      float sc0 = scv[lane], sc1 = scv[lane + 64];
      float lg0 = mk0 ? NEGV : sc0;
      float lg1 = mk1 ? NEGV : sc1;
      float v0g = g0 + lg0, v1g = g1 + lg1;
      float v; int idx;
      if (v1g > v0g) { v = v1g; idx = lane + 64; } else { v = v0g; idx = lane; }
      float mx = fmaxf(lg0, lg1);
#pragma unroll
      for (int off = 1; off < 64; off <<= 1) {
        float ov = __shfl_xor(v, off);
        int oi = __shfl_xor(idx, off);
        if (ov > v || (ov == v && oi < idx)) { v = ov; idx = oi; }
        mx = fmaxf(mx, __shfl_xor(mx, off));
      }
      int a = d ? 0 : idx;
      if (wave == 0) {
        float e = expf(lg0 - mx) + expf(lg1 - mx);
#pragma unroll
        for (int off = 1; off < 64; off <<= 1) e += __shfl_xor(e, off);
        if (lane == 0) {
          float sel = d ? 0.f : ((scv[idx] - mx) - logf(e));
          lps += sel;
          acts[step] = a;
          doneFlag = d;
        }
      }
      if (!d) {
        if (a == 0) { rc = capv; at = 1; }
        else {
          rc = rc - dem[a];
          at = 0; vc = vc + 1;
          if (a < 64) vism0 |= (1ull << a); else vism1 |= (1ull << (a - 64));
        }
      }
      done = d;
    }
    rslot = wslot;
  }

  __syncthreads();
  out[(size_t)b * 256 + t] = (float)acts[t];
  if (t == 0) out[(size_t)1024 * 256 + b] = lps;
}

extern "C" void kernel_launch(void* const* d_in, const int* in_sizes, int n_in,
                              void* d_out, int out_size, void* d_ws, size_t ws_size,
                              hipStream_t stream) {
  (void)in_sizes; (void)n_in; (void)out_size; (void)ws_size;
  const float* coords  = (const float*)d_in[0];
  const float* demands = (const float*)d_in[1];
  const float* caps    = (const float*)d_in[2];
  const float* W_emb   = (const float*)d_in[3];
  const float* b_emb   = (const float*)d_in[4];
  const float* Wq      = (const float*)d_in[5];
  const float* bq      = (const float*)d_in[6];
  const float* Wk      = (const float*)d_in[7];
  const float* bk      = (const float*)d_in[8];
  const float* Wv      = (const float*)d_in[9];
  const float* bv      = (const float*)d_in[10];
  const float* Wp1     = (const float*)d_in[11];
  const float* bp1     = (const float*)d_in[12];
  const float* Wp2     = (const float*)d_in[13];
  const float* bp2     = (const float*)d_in[14];

  float* ws = (float*)d_ws;
  const size_t R = (size_t)1024 * 128 * 128;  // 64 MiB per region
  float* R0 = ws;           // Q -> att_emb -> A1
  float* R1 = ws + R;       // K -> P
  float* R2 = ws + 2 * R;   // V

  pn_e1<<<1024, 256, 0, stream>>>(coords, demands, W_emb, b_emb, Wq, bq, Wk, bk, Wv, bv, R0, R1, R2);
  pn_e2<<<1024, 256, 0, stream>>>(R0, R1, R2, R0);
  pn_e3<<<1024, 256, 0, stream>>>(R0, Wp1, bp1, R0, R1);
  pn_decode<<<1024, 256, 0, stream>>>(R0, R1, demands, caps, Wp2, bp2, (float*)d_out);
}

// Round 9
// 2141.769 us; speedup vs baseline: 5.2041x; 1.0741x over previous
//
#include <hip/hip_runtime.h>
#include <stdint.h>
#include <stddef.h>

// BaselinePointerNetwork: B=1024, N=128, H=128, T=256
// Pipeline: e1 (emb,Q,K,V) -> e2 (attention -> att_emb) -> e3 (A1, P) -> decode
// ws regions (64MiB each): R0 = Q -> att -> A1, R1 = K -> P, R2 = V
// RNG: JAX threefry2x32, PARTITIONABLE semantics:
//   split (foldlike): key_t = (o0,o1) of tf(key,(0,t))
//   random_bits(32):  bits  = o0 ^ o1 of tf(key_t,(hi(i),lo(i))), i = b*128+n

#define NEGV (-1e9f)

__device__ __forceinline__ uint32_t rotl32(uint32_t v, int d) { return (v << d) | (v >> (32 - d)); }

__device__ __forceinline__ void threefry2x32(uint32_t k0, uint32_t k1, uint32_t c0, uint32_t c1,
                                             uint32_t& o0, uint32_t& o1) {
  uint32_t k2 = k0 ^ k1 ^ 0x1BD11BDAu;
  uint32_t x0 = c0 + k0, x1 = c1 + k1;
  x0 += x1; x1 = rotl32(x1, 13); x1 ^= x0;
  x0 += x1; x1 = rotl32(x1, 15); x1 ^= x0;
  x0 += x1; x1 = rotl32(x1, 26); x1 ^= x0;
  x0 += x1; x1 = rotl32(x1, 6);  x1 ^= x0;
  x0 += k1; x1 += k2 + 1u;
  x0 += x1; x1 = rotl32(x1, 17); x1 ^= x0;
  x0 += x1; x1 = rotl32(x1, 29); x1 ^= x0;
  x0 += x1; x1 = rotl32(x1, 16); x1 ^= x0;
  x0 += x1; x1 = rotl32(x1, 24); x1 ^= x0;
  x0 += k2; x1 += k0 + 2u;
  x0 += x1; x1 = rotl32(x1, 13); x1 ^= x0;
  x0 += x1; x1 = rotl32(x1, 15); x1 ^= x0;
  x0 += x1; x1 = rotl32(x1, 26); x1 ^= x0;
  x0 += x1; x1 = rotl32(x1, 6);  x1 ^= x0;
  x0 += k0; x1 += k1 + 3u;
  x0 += x1; x1 = rotl32(x1, 17); x1 ^= x0;
  x0 += x1; x1 = rotl32(x1, 29); x1 ^= x0;
  x0 += x1; x1 = rotl32(x1, 16); x1 ^= x0;
  x0 += x1; x1 = rotl32(x1, 24); x1 ^= x0;
  x0 += k1; x1 += k2 + 4u;
  x0 += x1; x1 = rotl32(x1, 13); x1 ^= x0;
  x0 += x1; x1 = rotl32(x1, 15); x1 ^= x0;
  x0 += x1; x1 = rotl32(x1, 26); x1 ^= x0;
  x0 += x1; x1 = rotl32(x1, 6);  x1 ^= x0;
  x0 += k2; x1 += k0 + 5u;
  o0 = x0; o1 = x1;
}

__device__ __forceinline__ float gumbel_from(uint32_t kA, uint32_t kB, uint32_t idx) {
  uint32_t o0, o1;
  threefry2x32(kA, kB, 0u, idx, o0, o1);
  uint32_t bits = o0 ^ o1;                 // partitionable: xor of both output words
  uint32_t mb = bits >> 9;
  float u = (mb == 0u) ? 1.17549435e-38f : (float)mb * 1.1920928955078125e-07f;
  return -logf(-logf(u));
}

// out[n][h] = sum_k Alds[n][k]*W[k][h] + bias[h]  (round-5 version; no reg prefetch)
__device__ void mm128(const float* Alds, float* wst,
                      const float* __restrict__ W, const float* __restrict__ bias,
                      float* outg, int t) {
  int wv = t >> 6, lane = t & 63;
  int j0 = lane * 2;
  float b0 = 0.f, b1 = 0.f;
  if (bias) { b0 = bias[j0]; b1 = bias[j0 + 1]; }
  int r0 = wv * 32;
  float acc0[4][8], acc1[4][8];
#pragma unroll
  for (int g = 0; g < 4; ++g)
#pragma unroll
    for (int r = 0; r < 8; ++r) { acc0[g][r] = b0; acc1[g][r] = b1; }
  for (int ks = 0; ks < 128; ks += 16) {
    __syncthreads();
    for (int i = t; i < 2048; i += 256) wst[i] = W[ks * 128 + i];
    __syncthreads();
#pragma unroll
    for (int k4 = 0; k4 < 16; k4 += 4) {
      float2 w[4];
#pragma unroll
      for (int kk = 0; kk < 4; ++kk) w[kk] = *(const float2*)&wst[(k4 + kk) * 128 + j0];
#pragma unroll
      for (int g = 0; g < 4; ++g)
#pragma unroll
        for (int r = 0; r < 8; ++r) {
          float4 a = *(const float4*)&Alds[(r0 + g * 8 + r) * 128 + ks + k4];
          acc0[g][r] = fmaf(a.x, w[0].x, acc0[g][r]); acc1[g][r] = fmaf(a.x, w[0].y, acc1[g][r]);
          acc0[g][r] = fmaf(a.y, w[1].x, acc0[g][r]); acc1[g][r] = fmaf(a.y, w[1].y, acc1[g][r]);
          acc0[g][r] = fmaf(a.z, w[2].x, acc0[g][r]); acc1[g][r] = fmaf(a.z, w[2].y, acc1[g][r]);
          acc0[g][r] = fmaf(a.w, w[3].x, acc0[g][r]); acc1[g][r] = fmaf(a.w, w[3].y, acc1[g][r]);
        }
    }
  }
#pragma unroll
  for (int g = 0; g < 4; ++g)
#pragma unroll
    for (int r = 0; r < 8; ++r) {
      int n = r0 + g * 8 + r;
      float2 o; o.x = acc0[g][r]; o.y = acc1[g][r];
      *(float2*)&outg[n * 128 + j0] = o;
    }
}

// ---- E1: emb -> Q, K, V ----
__global__ __launch_bounds__(256, 2) void pn_e1(
    const float* __restrict__ coords, const float* __restrict__ demands,
    const float* __restrict__ W_emb, const float* __restrict__ b_emb,
    const float* __restrict__ Wq, const float* __restrict__ bq,
    const float* __restrict__ Wk, const float* __restrict__ bk,
    const float* __restrict__ Wv, const float* __restrict__ bv,
    float* Qo, float* Ko, float* Vo) {
  __shared__ float emb[128 * 128];
  __shared__ float wst[16 * 128];
  __shared__ float nfx[128], nfy[128], nfd[128];
  int b = blockIdx.x, t = threadIdx.x;
  if (t < 128) {
    float2 c = ((const float2*)coords)[b * 128 + t];
    nfx[t] = c.x; nfy[t] = c.y; nfd[t] = demands[b * 128 + t];
  }
  __syncthreads();
  {
    int h = t >> 1, n0 = (t & 1) * 64;
    float w0 = W_emb[h], w1 = W_emb[128 + h], w2 = W_emb[256 + h], be = b_emb[h];
    for (int n = n0; n < n0 + 64; ++n) {
      float e = nfx[n] * w0;
      e = fmaf(nfy[n], w1, e);
      e = fmaf(nfd[n], w2, e);
      e = e + be;
      emb[n * 128 + h] = e;
    }
  }
  __syncthreads();
  mm128(emb, wst, Wq, bq, Qo + (size_t)b * 16384, t);
  mm128(emb, wst, Wk, bk, Ko + (size_t)b * 16384, t);
  mm128(emb, wst, Wv, bv, Vo + (size_t)b * 16384, t);
}

// ---- E2: att_emb = softmax(Q K^T / sqrt(H)) @ V ----
__global__ __launch_bounds__(256, 2) void pn_e2(
    const float* Qg, const float* __restrict__ Kg, const float* __restrict__ Vg, float* atto) {
  __shared__ float Ks[128 * 132];
  __shared__ float qb[4 * 512];
  int b = blockIdx.x, t = threadIdx.x;
  int wv = t >> 6, lane = t & 63;
  const float sden = sqrtf(128.0f);
  for (int i = t; i < 16384; i += 256) {
    int m = i >> 7, k = i & 127;
    Ks[m * 132 + k] = Kg[(size_t)b * 16384 + i];
  }
  __syncthreads();
  const float* Vb = Vg + (size_t)b * 16384;
  for (int pass = 0; pass < 8; ++pass) {
    int nb = pass * 16 + wv * 4;
    for (int i = lane; i < 512; i += 64) qb[wv * 512 + i] = Qg[(size_t)b * 16384 + nb * 128 + i];
    __syncthreads();
    float s0[4] = {0.f, 0.f, 0.f, 0.f}, s1[4] = {0.f, 0.f, 0.f, 0.f};
    for (int k = 0; k < 128; k += 4) {
      float4 ka = *(const float4*)&Ks[lane * 132 + k];
      float4 kb = *(const float4*)&Ks[(lane + 64) * 132 + k];
#pragma unroll
      for (int r = 0; r < 4; ++r) {
        float4 q = *(const float4*)&qb[wv * 512 + r * 128 + k];
        s0[r] = fmaf(q.x, ka.x, s0[r]); s0[r] = fmaf(q.y, ka.y, s0[r]);
        s0[r] = fmaf(q.z, ka.z, s0[r]); s0[r] = fmaf(q.w, ka.w, s0[r]);
        s1[r] = fmaf(q.x, kb.x, s1[r]); s1[r] = fmaf(q.y, kb.y, s1[r]);
        s1[r] = fmaf(q.z, kb.z, s1[r]); s1[r] = fmaf(q.w, kb.w, s1[r]);
      }
    }
    float p0[4], p1[4];
#pragma unroll
    for (int r = 0; r < 4; ++r) {
      float a0 = s0[r] / sden, a1 = s1[r] / sden;
      float mx = fmaxf(a0, a1);
#pragma unroll
      for (int off = 1; off < 64; off <<= 1) mx = fmaxf(mx, __shfl_xor(mx, off));
      float e0 = expf(a0 - mx), e1 = expf(a1 - mx);
      float sm = e0 + e1;
#pragma unroll
      for (int off = 1; off < 64; off <<= 1) sm += __shfl_xor(sm, off);
      p0[r] = e0 / sm; p1[r] = e1 / sm;
    }
#pragma unroll
    for (int r = 0; r < 4; ++r) {
      qb[wv * 512 + r * 128 + lane] = p0[r];
      qb[wv * 512 + r * 128 + lane + 64] = p1[r];
    }
    __syncthreads();
    float o0[4] = {0.f, 0.f, 0.f, 0.f}, o1[4] = {0.f, 0.f, 0.f, 0.f};
    for (int m4 = 0; m4 < 128; m4 += 4) {
      float4 p[4];
#pragma unroll
      for (int r = 0; r < 4; ++r) p[r] = *(const float4*)&qb[wv * 512 + r * 128 + m4];
#pragma unroll
      for (int mm = 0; mm < 4; ++mm) {
        float v0 = Vb[(m4 + mm) * 128 + lane];
        float v1 = Vb[(m4 + mm) * 128 + lane + 64];
#pragma unroll
        for (int r = 0; r < 4; ++r) {
          float pv = (mm == 0) ? p[r].x : (mm == 1) ? p[r].y : (mm == 2) ? p[r].z : p[r].w;
          o0[r] = fmaf(pv, v0, o0[r]);
          o1[r] = fmaf(pv, v1, o1[r]);
        }
      }
    }
#pragma unroll
    for (int r = 0; r < 4; ++r) {
      atto[(size_t)b * 16384 + (nb + r) * 128 + lane] = o0[r];
      atto[(size_t)b * 16384 + (nb + r) * 128 + lane + 64] = o1[r];
    }
    __syncthreads();
  }
}

// ---- E3: A1 = att@Wp1[:128] + bp1 ; P = att@Wp1[128:] ----
__global__ __launch_bounds__(256, 2) void pn_e3(
    const float* attg, const float* __restrict__ Wp1,
    const float* __restrict__ bp1, float* A1o, float* Po) {
  __shared__ float att[128 * 128];
  __shared__ float wst[16 * 128];
  int b = blockIdx.x, t = threadIdx.x;
  for (int i = t; i < 16384; i += 256) att[i] = attg[(size_t)b * 16384 + i];
  __syncthreads();
  mm128(att, wst, Wp1, bp1, A1o + (size_t)b * 16384, t);
  mm128(att, wst, Wp1 + 16384, (const float*)0, Po + (size_t)b * 16384, t);
}

// ---- decode v8: v7 structure with the scv[64..127] bug fixed ----
// rf[128] union:
//   waves 0-1 (t<128):  rf[0..63]  = A1[nrow][half*64..+64)      (nrow = t>>1, 0..63)
//                       rf[64..127]= A1[nrow+64][half*64..+64)   <- v7 forgot these
//   waves 2-3 (t>=128): rf[0..127] = P column h = t-128
// Phase A: waves 2-3 -> c1 (pure-VALU masked register chain, SGPR bit selects);
//          waves 0-1 -> next-step gumbel prefetch (triple-buffered gv).
// Phase B: waves 0-1, TWO nodes per thread pair (nrow, nrow+64); per-node op
//          sequence identical to v6 (single acc, ascending i) -> bit-exact.
// Phase C: all waves replicated state; wave0 lane0 writes acts/lps/doneFlag.
// Hazards identical to v7 (audited in r7 notes).
__global__ __launch_bounds__(256, 2) void pn_decode(
    const float* __restrict__ A1g, const float* __restrict__ Pg,
    const float* __restrict__ demands, const float* __restrict__ caps,
    const float* __restrict__ Wp2, const float* __restrict__ bp2, float* out) {
  __shared__ __align__(16) float c1[128];
  __shared__ __align__(16) float wp2s[128];
  __shared__ float scv[128];
  __shared__ float dem[128];
  __shared__ float gv[3][128];                   // triple-buffered gumbels
  __shared__ int acts[256];
  __shared__ uint32_t keyA[256], keyB[256];
  __shared__ int doneFlag;

  int b = blockIdx.x, t = threadIdx.x;
  int wave = t >> 6, lane = t & 63;
  { uint32_t o0, o1; threefry2x32(0u, 42u, 0u, (uint32_t)t, o0, o1); keyA[t] = o0; keyB[t] = o1; }
  if (t < 128) { dem[t] = demands[b * 128 + t]; wp2s[t] = Wp2[t]; }
  acts[t] = 0;
  if (t == 0) doneFlag = 0;

  int nrow = t >> 1, half = t & 1;
  float rf[128];
  if (t < 128) {
    const float4* asrc0 = (const float4*)(A1g + (size_t)b * 16384 + nrow * 128 + half * 64);
    const float4* asrc1 = (const float4*)(A1g + (size_t)b * 16384 + (nrow + 64) * 128 + half * 64);
#pragma unroll
    for (int j = 0; j < 16; ++j) {
      float4 v = asrc0[j];
      rf[4 * j] = v.x; rf[4 * j + 1] = v.y; rf[4 * j + 2] = v.z; rf[4 * j + 3] = v.w;
      float4 w = asrc1[j];
      rf[64 + 4 * j] = w.x; rf[64 + 4 * j + 1] = w.y; rf[64 + 4 * j + 2] = w.z; rf[64 + 4 * j + 3] = w.w;
    }
  } else {
    int h = t - 128;
    const float* pc = Pg + (size_t)b * 16384 + h;   // column h, lanes coalesce per n
#pragma unroll
    for (int n = 0; n < 128; ++n) rf[n] = pc[n * 128];
  }
  float capv = caps[b];
  float bp2v = bp2[0];
  float dem0 = demands[b * 128 + lane];        // n0 = lane   (all waves: C masks)
  float dem1 = demands[b * 128 + lane + 64];   // n1 = lane + 64
  // replicated state, uniform within each wave
  unsigned long long vism0 = 0ull, vism1 = 0ull;
  float rc = capv, lps = 0.f;
  int at = 1, done = 0, vc = 0;
  __syncthreads();
  // step-0 gumbels -> slot 0 (ordered vs C(0) reads by bar1(0)+bar2(0))
  if (t < 128) gv[0][t] = gumbel_from(keyA[0], keyB[0], (uint32_t)(b * 128 + t));

  int rslot = 0;
  for (int step = 0; step < 256; ++step) {
    int wslot = rslot + 1; if (wslot == 3) wslot = 0;
    if (t >= 128) {
      // A: c1[h] = masked ascending-n register chain / cnt  (zero LDS reads)
      uint32_t m0 = __builtin_amdgcn_readfirstlane((uint32_t)(vism0 & 0xffffffffull));
      uint32_t m1 = __builtin_amdgcn_readfirstlane((uint32_t)(vism0 >> 32));
      uint32_t m2 = __builtin_amdgcn_readfirstlane((uint32_t)(vism1 & 0xffffffffull));
      uint32_t m3 = __builtin_amdgcn_readfirstlane((uint32_t)(vism1 >> 32));
      float cnt = fmaxf((float)(128 - vc), 1.f);
      float acc = 0.f;
#pragma unroll
      for (int n = 0; n < 128; ++n) {
        uint32_t mw = (n < 32) ? m0 : (n < 64) ? m1 : (n < 96) ? m2 : m3;
        float s = ((mw >> (n & 31)) & 1u) ? 0.f : 1.f;
        acc = fmaf(rf[n], s, acc);
      }
      c1[t - 128] = acc / cnt;
    } else if (step < 255) {
      gv[wslot][t] = gumbel_from(keyA[step + 1], keyB[step + 1], (uint32_t)(b * 128 + t));
    }
    __syncthreads();  // bar1
    if (doneFlag) break;

    if (t < 128) {
      // B: two nodes per thread pair; per-node op order identical to v6
      const float* crow = &c1[half * 64];
      const float* wrow = &wp2s[half * 64];
      float acca = 0.f, accb = 0.f;
#pragma unroll
      for (int q = 0; q < 16; ++q) {
        float4 c4 = *(const float4*)&crow[q * 4];
        float4 w4 = *(const float4*)&wrow[q * 4];
        float x;
        x = rf[4 * q] + c4.x;          x = fmaxf(x, 0.f); acca = fmaf(x, w4.x, acca);
        x = rf[4 * q + 1] + c4.y;      x = fmaxf(x, 0.f); acca = fmaf(x, w4.y, acca);
        x = rf[4 * q + 2] + c4.z;      x = fmaxf(x, 0.f); acca = fmaf(x, w4.z, acca);
        x = rf[4 * q + 3] + c4.w;      x = fmaxf(x, 0.f); acca = fmaf(x, w4.w, acca);
        x = rf[64 + 4 * q] + c4.x;     x = fmaxf(x, 0.f); accb = fmaf(x, w4.x, accb);
        x = rf[64 + 4 * q + 1] + c4.y; x = fmaxf(x, 0.f); accb = fmaf(x, w4.y, accb);
        x = rf[64 + 4 * q + 2] + c4.z; x = fmaxf(x, 0.f); accb = fmaf(x, w4.z, accb);
        x = rf[64 + 4 * q + 3] + c4.w; x = fmaxf(x, 0.f); accb = fmaf(x, w4.w, accb);
      }
      float oa = __shfl_xor(acca, 1);
      float ob = __shfl_xor(accb, 1);
      if (half == 0) {
        scv[nrow] = (acca + oa) + bp2v;
        scv[nrow + 64] = (accb + ob) + bp2v;
      }
    }
    __syncthreads();  // bar2

    // C: all waves replicated: masks + ballot + argmax + state; wave0 lps/acts
    {
      float g0 = gv[rslot][lane], g1 = gv[rslot][lane + 64];
      bool mk0 = (lane == 0) ? (at != 0)
                             : ((((vism0 >> lane) & 1ull) != 0ull) || (dem0 > rc));
      bool mk1 = (((vism1 >> lane) & 1ull) != 0ull) || (dem1 > rc);
      unsigned long long bl0 = __ballot(mk0 ? 1 : 0);
      unsigned long long bl1 = __ballot(mk1 ? 1 : 0);
      int d = done;
      if (vc == 127 && at) d = 1;
      if ((bl0 == ~0ull) && (bl1 == ~0ull) && at) d = 1;
      if (lane == 0) mk0 = (at && !d);
      float sc0 = scv[lane], sc1 = scv[lane + 64];
      float lg0 = mk0 ? NEGV : sc0;
      float lg1 = mk1 ? NEGV : sc1;
      float v0g = g0 + lg0, v1g = g1 + lg1;
      float v; int idx;
      if (v1g > v0g) { v = v1g; idx = lane + 64; } else { v = v0g; idx = lane; }
      float mx = fmaxf(lg0, lg1);
#pragma unroll
      for (int off = 1; off < 64; off <<= 1) {
        float ov = __shfl_xor(v, off);
        int oi = __shfl_xor(idx, off);
        if (ov > v || (ov == v && oi < idx)) { v = ov; idx = oi; }
        mx = fmaxf(mx, __shfl_xor(mx, off));
      }
      int a = d ? 0 : idx;
      if (wave == 0) {
        float e = expf(lg0 - mx) + expf(lg1 - mx);
#pragma unroll
        for (int off = 1; off < 64; off <<= 1) e += __shfl_xor(e, off);
        if (lane == 0) {
          float sel = d ? 0.f : ((scv[idx] - mx) - logf(e));
          lps += sel;
          acts[step] = a;
          doneFlag = d;
        }
      }
      if (!d) {
        if (a == 0) { rc = capv; at = 1; }
        else {
          rc = rc - dem[a];
          at = 0; vc = vc + 1;
          if (a < 64) vism0 |= (1ull << a); else vism1 |= (1ull << (a - 64));
        }
      }
      done = d;
    }
    rslot = wslot;
  }

  __syncthreads();
  out[(size_t)b * 256 + t] = (float)acts[t];
  if (t == 0) out[(size_t)1024 * 256 + b] = lps;
}

extern "C" void kernel_launch(void* const* d_in, const int* in_sizes, int n_in,
                              void* d_out, int out_size, void* d_ws, size_t ws_size,
                              hipStream_t stream) {
  (void)in_sizes; (void)n_in; (void)out_size; (void)ws_size;
  const float* coords  = (const float*)d_in[0];
  const float* demands = (const float*)d_in[1];
  const float* caps    = (const float*)d_in[2];
  const float* W_emb   = (const float*)d_in[3];
  const float* b_emb   = (const float*)d_in[4];
  const float* Wq      = (const float*)d_in[5];
  const float* bq      = (const float*)d_in[6];
  const float* Wk      = (const float*)d_in[7];
  const float* bk      = (const float*)d_in[8];
  const float* Wv      = (const float*)d_in[9];
  const float* bv      = (const float*)d_in[10];
  const float* Wp1     = (const float*)d_in[11];
  const float* bp1     = (const float*)d_in[12];
  const float* Wp2     = (const float*)d_in[13];
  const float* bp2     = (const float*)d_in[14];

  float* ws = (float*)d_ws;
  const size_t R = (size_t)1024 * 128 * 128;  // 64 MiB per region
  float* R0 = ws;           // Q -> att_emb -> A1
  float* R1 = ws + R;       // K -> P
  float* R2 = ws + 2 * R;   // V

  pn_e1<<<1024, 256, 0, stream>>>(coords, demands, W_emb, b_emb, Wq, bq, Wk, bk, Wv, bv, R0, R1, R2);
  pn_e2<<<1024, 256, 0, stream>>>(R0, R1, R2, R0);
  pn_e3<<<1024, 256, 0, stream>>>(R0, Wp1, bp1, R0, R1);
  pn_decode<<<1024, 256, 0, stream>>>(R0, R1, demands, caps, Wp2, bp2, (float*)d_out);
}